// Round 5
// baseline (604.813 us; speedup 1.0000x reference)
//
#include <hip/hip_runtime.h>

// Linear_AB_I8_DE_F32: y[m,n] = 0.01 * sum_k x8[m,k]*w8[n,k] + bias[n]
// M=4096, N=11008, K=4096. int8 values in int32 containers.
//
// R8: de-serialize by construction.
//   - B operand loaded GLOBAL->VGPR directly (per-lane row pointers; panel is
//     L2/LLC-resident). LDS holds only A (2 x 32KB dbuf). LDS-port traffic
//     drops from ~2770 cy/K-tile (co-equal with MFMA) to ~1875.
//   - 2 barriers per K-tile (was 8): the only cross-wave hazards left are the
//     two A-unit RAW gates (GA0 before a0-reads, GA1 before a1-reads), each a
//     counted VMCNT + s_barrier. All WAR cases separated by >= 1 barrier.
//   - four 16-MFMA clusters back-to-back per tile; k-outer order; compiler
//     interleaves ds_read/global_load waits finely inside the clusters.
//   - prefetch flight = 1 full tile (~3800 cy) for A-stages and B-loads;
//     vmcnt never 0 in steady state; ra reused a0->a1 (fits 128 arch VGPR).

#define M_DIM 4096
#define N_DIM 11008
#define K_DIM 4096
#define BM 256
#define BN 256
#define BK 128                  // bytes of K per tile (int8)
#define NT (K_DIM / BK)         // 32 K-tiles
#define ALPHA 0.01f

typedef __attribute__((ext_vector_type(4))) int i32x4;

static __device__ __forceinline__ int pack4(int4 v) {
    return (v.x & 0xff) | ((v.y & 0xff) << 8) |
           ((v.z & 0xff) << 16) | ((unsigned)(v.w & 0xff) << 24);
}

// ---------------- fused pack: 16 int32 -> 16 int8 per thread ----------------
__global__ __launch_bounds__(256) void pack_i8_kernel(
    const int4* __restrict__ x, int4* __restrict__ xout, int n16x,
    const int4* __restrict__ w, int4* __restrict__ wout, int n16_total)
{
    int i = blockIdx.x * blockDim.x + threadIdx.x;
    if (i >= n16_total) return;
    const int4* src;
    int4* dst;
    int idx;
    if (i < n16x) { src = x; dst = xout; idx = i; }
    else          { src = w; dst = wout; idx = i - n16x; }
    const int4* p = src + (size_t)4 * idx;
    int4 a = p[0], b = p[1], c = p[2], d = p[3];
    int4 r;
    r.x = pack4(a); r.y = pack4(b); r.z = pack4(c); r.w = pack4(d);
    dst[idx] = r;
}

// ---------------- GEMM ----------------
// A stage units: 16 KB = 16 8-row groups; each wave covers 2 (u_=0,1).
//   GA0: rows {0-63,128-191} (a0-read rows); GA1: rows {64-127,192-255} (a1).
#define GA0 (s_ + 8 * (s_ >> 3))
#define GA1 (8 + s_ + 8 * (s_ >> 3))

#define STAGE(dstArr, srcB, T, GEXPR)                                          \
    _Pragma("unroll") for (int u_ = 0; u_ < 2; u_++) {                         \
        const int s_ = u_ * 8 + wave;                                          \
        const int G_ = (GEXPR);                                                \
        __builtin_amdgcn_global_load_lds(                                      \
            (const __attribute__((address_space(1))) void*)(                   \
                (srcB) + (size_t)(G_ * 8 + (lane >> 3)) * K_DIM +              \
                (size_t)(T) * BK + sch16),                                     \
            (__attribute__((address_space(3))) void*)((dstArr) + G_ * 1024 +   \
                                                      lane * 16),              \
            16, 0, 0);                                                         \
    }

#define READ_A(Arr, dst, IB)                                                   \
    _Pragma("unroll") for (int i_ = 0; i_ < 4; i_++)                           \
        _Pragma("unroll") for (int k_ = 0; k_ < 2; k_++)                       \
            dst[i_][k_] = *(const i32x4*)((Arr) + aoff[k_] + ((IB) + i_) * 2048);

// B fragment loads: global -> VGPR. bptr[j] = row base + lquad*16.
#define BLOAD01(dst, IMM)                                                      \
    _Pragma("unroll") for (int j_ = 0; j_ < 2; j_++)                           \
        _Pragma("unroll") for (int k_ = 0; k_ < 2; k_++)                       \
            dst[j_][k_] = *(const i32x4*)(bptr[j_] + (IMM) + k_ * 64);
#define BLOAD23(dst, IMM)                                                      \
    _Pragma("unroll") for (int j_ = 0; j_ < 2; j_++)                           \
        _Pragma("unroll") for (int k_ = 0; k_ < 2; k_++)                       \
            dst[j_][k_] = *(const i32x4*)(bptr[2 + j_] + (IMM) + k_ * 64);

#define MFMA_G(af, bf, IB, JB)                                                 \
    __builtin_amdgcn_s_setprio(1);                                             \
    _Pragma("unroll") for (int k_ = 0; k_ < 2; k_++)                           \
        _Pragma("unroll") for (int i_ = 0; i_ < 4; i_++)                       \
            _Pragma("unroll") for (int j_ = 0; j_ < 2; j_++)                   \
                acc[(IB) + i_][(JB) + j_] =                                    \
                    __builtin_amdgcn_mfma_i32_16x16x64_i8(                     \
                        af[i_][k_], bf[j_][k_],                                \
                        acc[(IB) + i_][(JB) + j_], 0, 0, 0);                   \
    __builtin_amdgcn_s_setprio(0);

#define VMCNT_(N) asm volatile("s_waitcnt vmcnt(" #N ")" ::: "memory")
#define VMCNT(N) VMCNT_(N)
#define BAR() __builtin_amdgcn_s_barrier()
#define SCHEDB() __builtin_amdgcn_sched_barrier(0)

// One K-tile, 2 barriers. CA = current A buf, NA = stage-dest A buf.
// B01c = this tile's b01 regs, B01n = buffer receiving b01(T+1).
// Issue order/tile (STG=1): [2A GA0'][4b b01'][2A GA1'][4b b23'] = 12.
// G2 (mid): GA1(T) staged last tile -> V2 = newer = 4+2+4+2 = 12.
// G1 (end): GA0(T+1) staged at top -> V4 = newer = 4+2+4 = 10.
#define TILE(CA, NA, B01c, B01n, T, KOFF, STG, V2, V4)                         \
    {                                                                          \
        READ_A(CA, ra, 0);                              /* a0 */               \
        if (STG) { STAGE(NA, Abase, (T) + 1, GA0); }                           \
        MFMA_G(ra, B01c, 0, 0);                         /* a0 x b01 */         \
        MFMA_G(ra, rb23, 0, 2);                         /* a0 x b23 */         \
        if (STG) { BLOAD01(B01n, (KOFF) + 128);                                \
                   STAGE(NA, Abase, (T) + 1, GA1); }                           \
        VMCNT(V2);                                                             \
        SCHEDB();                                                              \
        BAR();                                          /* G2 gate */          \
        READ_A(CA, ra, 4);                              /* a1 */               \
        MFMA_G(ra, rb23, 4, 2);                         /* a1 x b23 */         \
        if (STG) { BLOAD23(rb23, (KOFF) + 128); }                              \
        MFMA_G(ra, B01c, 4, 0);                         /* a1 x b01 */         \
        VMCNT(V4);                                                             \
        SCHEDB();                                                              \
        BAR();                                          /* G1 gate */          \
    }

__global__ __launch_bounds__(512, 1) void gemm_i8_kernel(
    const char* __restrict__ A,     // [M][K] int8 row-major
    const char* __restrict__ B,     // [N][K] int8 row-major
    const float* __restrict__ bias, // [N]
    float* __restrict__ C)          // [M][N] fp32
{
    __shared__ __attribute__((aligned(16))) char As0[BM * BK]; // 32 KB
    __shared__ __attribute__((aligned(16))) char As1[BM * BK]; // 32 KB

    const int tid   = threadIdx.x;
    const int lane  = tid & 63;
    const int wave  = tid >> 6;
    const int waveM = (wave >> 2) * 128;   // 2x4 wave grid: 128x64 per wave
    const int waveN = (wave & 3) * 64;
    const int lrow  = lane & 15;
    const int lquad = lane >> 4;

    // bijective XCD swizzle: 688 = 8 * 86. XCD x owns M-panels {2x, 2x+1};
    // consecutive local pairs share a B-panel.
    const int bid = blockIdx.x;
    const int xcd = bid & 7;
    const int loc = bid >> 3;              // 0..85
    const int bm  = (2 * xcd + (loc & 1)) * BM;
    const int bn  = (loc >> 1) * BN;

    // A staging swizzle: LDS slot (row, p) holds global chunk p ^ (row&7).
    const int sch16 = ((lane & 7) ^ ((lane >> 3) & 7)) << 4;
    const char* Abase = A + (size_t)bm * K_DIM;

    // A frag read: global chunk (ks*4+lquad) of row r lives at slot
    // (ks*4+lquad)^(r&7); r&7 == lrow&7 for 16-aligned bases.
    int aoff[2];
#pragma unroll
    for (int ks = 0; ks < 2; ks++) {
        const int pos = ((ks * 4 + lquad) ^ (lrow & 7)) << 4;
        aoff[ks] = (waveM + lrow) * BK + pos;
    }

    // B row pointers: lane reads row (bn + waveN + j*16 + lrow), k-chunk
    // lquad*16 within each 64B k-slice. Bumped +256 per 2-tile iteration.
    const char* bptr[4];
#pragma unroll
    for (int j = 0; j < 4; j++)
        bptr[j] = B + (size_t)(bn + waveN + j * 16 + lrow) * K_DIM + lquad * 16;

    i32x4 acc[8][4] = {};
    i32x4 ra[4][2], rbA[2][2], rbB[2][2], rb23[2][2];

    // prologue: stage A(tile0); load b01(0)->rbA, b23(0)->rb23; drain once.
    STAGE(As0, Abase, 0, GA0);
    STAGE(As0, Abase, 0, GA1);
    BLOAD01(rbA, 0);
    BLOAD23(rb23, 0);
    VMCNT(0);
    BAR();

#pragma unroll 1
    for (int t = 0; t < NT - 4; t += 2) {
        TILE(As0, As1, rbA, rbB, t,     0,   1, 12, 10);
        TILE(As1, As0, rbB, rbA, t + 1, 128, 1, 12, 10);
#pragma unroll
        for (int j = 0; j < 4; j++) bptr[j] += 256;
    }
    // trailing 4 tiles (28..31): immediates grow, no pointer bump.
    TILE(As0, As1, rbA, rbB, NT - 4, 0,   1, 12, 10);
    TILE(As1, As0, rbB, rbA, NT - 3, 128, 1, 12, 10);
    TILE(As0, As1, rbA, rbB, NT - 2, 256, 1, 12, 10);
    TILE(As1, As0, rbB, rbA, NT - 1, 384, 0, 4, 0);

    // epilogue: C/D layout col=lane&15, row=(lane>>4)*4+reg
#pragma unroll
    for (int i = 0; i < 8; i++) {
        const int r0 = bm + waveM + i * 16 + lquad * 4;
#pragma unroll
        for (int j = 0; j < 4; j++) {
            const int c0 = bn + waveN + j * 16 + lrow;
            const float bv = bias[c0];
#pragma unroll
            for (int r = 0; r < 4; r++) {
                C[(size_t)(r0 + r) * N_DIM + c0] = ALPHA * (float)acc[i][j][r] + bv;
            }
        }
    }
}

extern "C" void kernel_launch(void* const* d_in, const int* in_sizes, int n_in,
                              void* d_out, int out_size, void* d_ws, size_t ws_size,
                              hipStream_t stream) {
    const int*   x    = (const int*)d_in[0];
    const int*   w    = (const int*)d_in[1];
    const float* bias = (const float*)d_in[2];
    float*       out  = (float*)d_out;

    char* Ap = (char*)d_ws;
    char* Wp = (char*)d_ws + (size_t)M_DIM * K_DIM;

    const int n16x = M_DIM * K_DIM / 16;          // 1,048,576
    const int n16w = N_DIM * K_DIM / 16;          // 2,818,048
    const int n16  = n16x + n16w;                 // 3,866,624 -> 15104 blocks
    pack_i8_kernel<<<n16 / 256, 256, 0, stream>>>(
        (const int4*)x, (int4*)Ap, n16x, (const int4*)w, (int4*)Wp, n16);

    // 688 blocks = 8 XCDs x 86 (bijective swizzle inside the kernel)
    gemm_i8_kernel<<<dim3((M_DIM / BM) * (N_DIM / BN)), 512, 0, stream>>>(
        Ap, Wp, bias, out);
}

// Round 6
// 533.922 us; speedup vs baseline: 1.1328x; 1.1328x over previous
//
#include <hip/hip_runtime.h>

// Linear_AB_I8_DE_F32: y[m,n] = 0.01 * sum_k x8[m,k]*w8[n,k] + bias[n]
// M=4096, N=11008, K=4096. int8 values in int32 containers.
//
// R9: cut LDS traffic — B never touches LDS.
//   Model: per K-tile MFMA floor 2613 cy/CU, but A+B-through-LDS moves
//   256KB/tile over the CU-shared LDS port (~2600 cy) -> serial alternation
//   = the stubborn 33%. i8's 2x compute rate makes bf16-tuned LDS structure
//   LDS-bound; fix = traffic, not schedule.
//   - W packed k-major: [k/64][n/16][(n&15)*64 + (k&63)] -> a wave's B-frag
//     load is ONE contiguous 1KB block per instr (fully coalesced, L2-resident,
//     TA pipe parallel to LDS). Kills R8's scattered-load failure.
//   - LDS holds only A (2 x 32KB dbuf): 160KB/tile (~1600cy) < MFMA 2613cy.
//   - 1 barrier + 1 vmcnt(8) per K-tile: only A RAW gates are cross-wave;
//     B-reg hazards are per-wave, compiler-counted.
//   - B fragment regs parity-dbuf (b01); b23 reloaded mid-tile after last use.

#define M_DIM 4096
#define N_DIM 11008
#define K_DIM 4096
#define BM 256
#define BN 256
#define BK 128                  // bytes of K per tile (int8)
#define NT (K_DIM / BK)         // 32 K-tiles
#define NBLK (N_DIM / 16)       // 688 n-blocks in packed W
#define KPBLK ((size_t)NBLK * 1024)   // 704512 B per k-block of packed W
#define ALPHA 0.01f

typedef __attribute__((ext_vector_type(4))) int i32x4;

static __device__ __forceinline__ int pack4(int4 v) {
    return (v.x & 0xff) | ((v.y & 0xff) << 8) |
           ((v.z & 0xff) << 16) | ((unsigned)(v.w & 0xff) << 24);
}

// ---------------- fused pack: 16 int32 -> 16 int8 per thread ----------------
// x -> linear row-major int8 (for A LDS staging).
// w -> k-packed fragment order: (n,k) at ((k>>6)*688 + (n>>4))*1024
//                                + (n&15)*64 + (k&63).
__global__ __launch_bounds__(256) void pack_i8_kernel(
    const int4* __restrict__ x, int4* __restrict__ xout, int n16x,
    const int4* __restrict__ w, char* __restrict__ wout, int n16_total)
{
    int i = blockIdx.x * blockDim.x + threadIdx.x;
    if (i >= n16_total) return;
    if (i < n16x) {
        const int4* p = x + (size_t)4 * i;
        int4 a = p[0], b = p[1], c = p[2], d = p[3];
        int4 r;
        r.x = pack4(a); r.y = pack4(b); r.z = pack4(c); r.w = pack4(d);
        xout[i] = r;
    } else {
        const int g = i - n16x;
        const int4* p = w + (size_t)4 * g;
        int4 a = p[0], b = p[1], c = p[2], d = p[3];
        int4 r;
        r.x = pack4(a); r.y = pack4(b); r.z = pack4(c); r.w = pack4(d);
        const int n  = g >> 8;              // K/16 = 256 16B-groups per row
        const int k0 = (g & 255) << 4;      // k byte offset of this group
        const size_t off = ((size_t)(k0 >> 6) * NBLK + (n >> 4)) * 1024
                         + (size_t)((n & 15) << 6) + (k0 & 63);
        *(int4*)(wout + off) = r;
    }
}

// ---------------- GEMM ----------------
// A stage units: 16 KB = 16 8-row groups; each wave covers 2 (u_=0,1).
//   GA0: rows {0-63,128-191} (a0-read rows); GA1: rows {64-127,192-255} (a1).
#define GA0 (s_ + 8 * (s_ >> 3))
#define GA1 (8 + s_ + 8 * (s_ >> 3))

#define STAGE(dstArr, T, GEXPR)                                                \
    _Pragma("unroll") for (int u_ = 0; u_ < 2; u_++) {                         \
        const int s_ = u_ * 8 + wave;                                          \
        const int G_ = (GEXPR);                                                \
        __builtin_amdgcn_global_load_lds(                                      \
            (const __attribute__((address_space(1))) void*)(                   \
                Abase + (size_t)(G_ * 8 + (lane >> 3)) * K_DIM +               \
                (size_t)(T) * BK + sch16),                                     \
            (__attribute__((address_space(3))) void*)((dstArr) + G_ * 1024 +   \
                                                      lane * 16),              \
            16, 0, 0);                                                         \
    }

#define READ_A(Arr, dst, IB)                                                   \
    _Pragma("unroll") for (int i_ = 0; i_ < 4; i_++)                           \
        _Pragma("unroll") for (int k_ = 0; k_ < 2; k_++)                       \
            dst[i_][k_] = *(const i32x4*)((Arr) + aoff[k_] + ((IB) + i_) * 2048);

// B fragment loads: one contiguous 1KB block per (j,ks). bp0/bp1 point at
// kblk 2T/2T+1 for the NEXT tile, lane offset pre-added.
#define BLOAD01(dst)                                                           \
    _Pragma("unroll") for (int j_ = 0; j_ < 2; j_++) {                         \
        dst[j_][0] = *(const i32x4*)(bp0 + j_ * 1024);                         \
        dst[j_][1] = *(const i32x4*)(bp1 + j_ * 1024);                         \
    }
#define BLOAD23(dst)                                                           \
    _Pragma("unroll") for (int j_ = 0; j_ < 2; j_++) {                         \
        dst[j_][0] = *(const i32x4*)(bp0 + 2048 + j_ * 1024);                  \
        dst[j_][1] = *(const i32x4*)(bp1 + 2048 + j_ * 1024);                  \
    }

#define MFMA_G(af, bf, IB, JB)                                                 \
    __builtin_amdgcn_s_setprio(1);                                             \
    _Pragma("unroll") for (int k_ = 0; k_ < 2; k_++)                           \
        _Pragma("unroll") for (int i_ = 0; i_ < 4; i_++)                       \
            _Pragma("unroll") for (int j_ = 0; j_ < 2; j_++)                   \
                acc[(IB) + i_][(JB) + j_] =                                    \
                    __builtin_amdgcn_mfma_i32_16x16x64_i8(                     \
                        af[i_][k_], bf[j_][k_],                                \
                        acc[(IB) + i_][(JB) + j_], 0, 0, 0);                   \
    __builtin_amdgcn_s_setprio(0);

#define VMCNT_(N) asm volatile("s_waitcnt vmcnt(" #N ")" ::: "memory")
#define VMCNT(N) VMCNT_(N)
#define BAR() __builtin_amdgcn_s_barrier()
#define SCHEDB() __builtin_amdgcn_sched_barrier(0)

// One K-tile, ONE barrier. CUR/NXT = A dbuf halves. B01c = this tile's b01
// regs, B01n = parity buffer receiving b01(T+1). rb23 single-buffered
// (reloaded for T+1 after its last use at G3).
// Gate: VMCNT(8) retires GA(T) (staged at T-1 post-bar; 8 newer loads =
// B01(T) 4 + B23(T) 4 always outstanding behind it).
#define TILE(CUR, NXT, B01c, B01n, T, STG)                                     \
    {                                                                          \
        VMCNT(8);                                                              \
        SCHEDB();                                                              \
        BAR();                                                                 \
        if (STG) {                                                             \
            STAGE(NXT, (T) + 1, GA0);                                          \
            STAGE(NXT, (T) + 1, GA1);                                          \
            BLOAD01(B01n);                                                     \
        }                                                                      \
        READ_A(CUR, ra0, 0);                                                   \
        MFMA_G(ra0, B01c, 0, 0);                        /* a0 x b01 */         \
        MFMA_G(ra0, rb23, 0, 2);                        /* a0 x b23 */         \
        READ_A(CUR, ra1, 4);                                                   \
        MFMA_G(ra1, rb23, 4, 2);                        /* a1 x b23 */         \
        if (STG) { BLOAD23(rb23); bp0 += 2 * KPBLK; bp1 += 2 * KPBLK; }        \
        MFMA_G(ra1, B01c, 4, 0);                        /* a1 x b01 */         \
    }

__global__ __launch_bounds__(512, 1) void gemm_i8_kernel(
    const char* __restrict__ A,     // [M][K] int8 row-major
    const char* __restrict__ B,     // packed W, k-major fragment order
    const float* __restrict__ bias, // [N]
    float* __restrict__ C)          // [M][N] fp32
{
    __shared__ __attribute__((aligned(16))) char As0[BM * BK]; // 32 KB
    __shared__ __attribute__((aligned(16))) char As1[BM * BK]; // 32 KB

    const int tid   = threadIdx.x;
    const int lane  = tid & 63;
    const int wave  = tid >> 6;
    const int waveM = (wave >> 2) * 128;   // 2x4 wave grid: 128x64 per wave
    const int waveN = (wave & 3) * 64;
    const int lrow  = lane & 15;
    const int lquad = lane >> 4;

    // bijective XCD swizzle: 688 = 8 * 86. XCD x owns M-panels {2x, 2x+1};
    // consecutive local pairs share a B-panel.
    const int bid = blockIdx.x;
    const int xcd = bid & 7;
    const int loc = bid >> 3;              // 0..85
    const int bm  = (2 * xcd + (loc & 1)) * BM;
    const int bn  = (loc >> 1) * BN;

    // A staging swizzle: LDS slot (row, p) holds global chunk p ^ (row&7).
    const int sch16 = ((lane & 7) ^ ((lane >> 3) & 7)) << 4;
    const char* Abase = A + (size_t)bm * K_DIM;

    // A frag read: global chunk (ks*4+lquad) of row r lives at slot
    // (ks*4+lquad)^(r&7); r&7 == lrow&7 for 16-aligned bases.
    int aoff[2];
#pragma unroll
    for (int ks = 0; ks < 2; ks++) {
        const int pos = ((ks * 4 + lquad) ^ (lrow & 7)) << 4;
        aoff[ks] = (waveM + lrow) * BK + pos;
    }

    // B pointers into packed W: kblk 0/1 of tile 0, n-block (bn+waveN)/16,
    // per-lane fragment offset (l&15)*64 + (l>>4)*16.
    const char* bp0 = B + ((size_t)((bn + waveN) >> 4)) * 1024
                    + (size_t)(((lane & 15) << 6) + ((lane >> 4) << 4));
    const char* bp1 = bp0 + KPBLK;

    i32x4 acc[8][4] = {};
    i32x4 ra0[4][2], ra1[4][2], rbA[2][2], rbB[2][2], rb23[2][2];

    // prologue: stage A(tile0); load b01(0)->rbA, b23(0)->rb23; bump to tile1.
    STAGE(As0, 0, GA0);
    STAGE(As0, 0, GA1);
    BLOAD01(rbA);
    BLOAD23(rb23);
    bp0 += 2 * KPBLK;
    bp1 += 2 * KPBLK;

#pragma unroll 1
    for (int t = 0; t < NT - 2; t += 2) {
        TILE(As0, As1, rbA, rbB, t,     1);
        TILE(As1, As0, rbB, rbA, t + 1, 1);
    }
    TILE(As0, As1, rbA, rbB, NT - 2, 1);
    TILE(As1, As0, rbB, rbA, NT - 1, 0);

    // epilogue: C/D layout col=lane&15, row=(lane>>4)*4+reg
#pragma unroll
    for (int i = 0; i < 8; i++) {
        const int r0 = bm + waveM + i * 16 + lquad * 4;
#pragma unroll
        for (int j = 0; j < 4; j++) {
            const int c0 = bn + waveN + j * 16 + lrow;
            const float bv = bias[c0];
#pragma unroll
            for (int r = 0; r < 4; r++) {
                C[(size_t)(r0 + r) * N_DIM + c0] = ALPHA * (float)acc[i][j][r] + bv;
            }
        }
    }
}

extern "C" void kernel_launch(void* const* d_in, const int* in_sizes, int n_in,
                              void* d_out, int out_size, void* d_ws, size_t ws_size,
                              hipStream_t stream) {
    const int*   x    = (const int*)d_in[0];
    const int*   w    = (const int*)d_in[1];
    const float* bias = (const float*)d_in[2];
    float*       out  = (float*)d_out;

    char* Ap = (char*)d_ws;
    char* Wp = (char*)d_ws + (size_t)M_DIM * K_DIM;

    const int n16x = M_DIM * K_DIM / 16;          // 1,048,576
    const int n16w = N_DIM * K_DIM / 16;          // 2,818,048
    const int n16  = n16x + n16w;                 // 3,866,624 -> 15104 blocks
    pack_i8_kernel<<<n16 / 256, 256, 0, stream>>>(
        (const int4*)x, (int4*)Ap, n16x, (const int4*)w, Wp, n16);

    // 688 blocks = 8 XCDs x 86 (bijective swizzle inside the kernel)
    gemm_i8_kernel<<<dim3((M_DIM / BM) * (N_DIM / BN)), 512, 0, stream>>>(
        Ap, Wp, bias, out);
}